// Round 1
// baseline (434.566 us; speedup 1.0000x reference)
//
#include <hip/hip_runtime.h>
#include <hip/hip_bf16.h>
#include <math.h>

// ws layout (floats): [0,32768) feat512; [32768,33792) angles; [33792,33856) qacc
// state ping-pong buffers at byte offset 4MB: SA, SB (each 64*65536 float2 = 33.55MB)

typedef _Float16 h2 __attribute__((ext_vector_type(2)));

__device__ __forceinline__ float2 cmulf(float2 a, float2 b){
    return make_float2(a.x*b.x - a.y*b.y, a.x*b.y + a.y*b.x);
}
__device__ __forceinline__ void cswap(float2& a, float2& b){ float2 t=a; a=b; b=t; }

// ---------------- zero small ws arrays ----------------
__global__ void k_zero(float* ws){
    int i = blockIdx.x*256 + threadIdx.x;
    if (i < 33856) ws[i] = 0.0f;
}

// ---------------- conv + relu + global-avg-pool ----------------
// grid 64*28 blocks, 256 threads. Each block: one sample, 112 output positions.
// Thread owns 2 channels; patch (4 positions) staged in LDS as f16.
__global__ __launch_bounds__(256) void k_conv(const float* __restrict__ x,
            const float* __restrict__ Wc, const float* __restrict__ bc,
            float* __restrict__ feat){
    __shared__ h2 ldsW[512*24];        // 49152 B
    __shared__ _Float16 ldsP[4][48];   // 4 positions x 48 halves
    int tid = threadIdx.x;
    int bx = blockIdx.x;
    int b = bx / 28, pb = bx % 28;
    // stage W as packed f16 pairs (coalesced float2 reads)
    for (int j = tid; j < 512*24; j += 256){
        float2 wv = ((const float2*)Wc)[j];
        h2 hv; hv.x = (_Float16)wv.x; hv.y = (_Float16)wv.y;
        ldsW[j] = hv;
    }
    __syncthreads();
    int ch0 = 2*tid, ch1 = ch0+1;
    h2 w0[24], w1[24];
    #pragma unroll
    for (int k=0;k<24;++k){ w0[k] = ldsW[ch0*24+k]; w1[k] = ldsW[ch1*24+k]; }
    float bias0 = bc[ch0], bias1 = bc[ch1];
    float pool0 = 0.f, pool1 = 0.f;
    for (int it=0; it<28; ++it){
        int p4 = pb*112 + it*4;              // first of 4 positions (56%4==0: same row)
        int oh = p4/56, ow4 = (p4%56)*4;     // input col base
        __syncthreads();
        if (tid < 192){
            int seg = tid >> 4;              // 0..11: c=seg>>2, r=seg&3
            int col = tid & 15;
            int cc = seg >> 2, r = seg & 3;
            float v = x[(((size_t)b*3 + cc)*224 + (oh*4 + r))*224 + ow4 + col];
            ldsP[col>>2][cc*16 + r*4 + (col&3)] = (_Float16)v;
        }
        __syncthreads();
        #pragma unroll
        for (int j=0;j<4;++j){
            h2 ph[24];
            uint4* pp = (uint4*)&ldsP[j][0];
            #pragma unroll
            for (int q=0;q<6;++q){
                union { uint4 u4; h2 h[4]; } cv; cv.u4 = pp[q];
                ph[q*4+0]=cv.h[0]; ph[q*4+1]=cv.h[1]; ph[q*4+2]=cv.h[2]; ph[q*4+3]=cv.h[3];
            }
            float d0 = 0.f, d1 = 0.f;
            #pragma unroll
            for (int k=0;k<24;++k){
#if __has_builtin(__builtin_amdgcn_fdot2)
                d0 = __builtin_amdgcn_fdot2(ph[k], w0[k], d0, false);
                d1 = __builtin_amdgcn_fdot2(ph[k], w1[k], d1, false);
#else
                d0 += (float)ph[k].x*(float)w0[k].x + (float)ph[k].y*(float)w0[k].y;
                d1 += (float)ph[k].x*(float)w1[k].x + (float)ph[k].y*(float)w1[k].y;
#endif
            }
            pool0 += fmaxf(d0 + bias0, 0.f);
            pool1 += fmaxf(d1 + bias1, 0.f);
        }
    }
    atomicAdd(&feat[b*512 + ch0], pool0);
    atomicAdd(&feat[b*512 + ch1], pool1);
}

// ---------------- reducer: tanh(feat/3136 @ Wr^T + br) * pi ----------------
__global__ __launch_bounds__(1024) void k_red(const float* __restrict__ feat,
        const float* __restrict__ Wr, const float* __restrict__ br,
        float* __restrict__ angles){
    int b = blockIdx.x;
    int tid = threadIdx.x;
    int w = tid >> 6, l = tid & 63;   // wave w handles wire w
    float acc = 0.f;
    #pragma unroll
    for (int k=0;k<8;++k){
        int idx = l + 64*k;
        acc += (feat[b*512 + idx] * (1.0f/3136.0f)) * Wr[w*512 + idx];
    }
    #pragma unroll
    for (int m=32;m>=1;m>>=1) acc += __shfl_xor(acc, m);
    if (l == 0){
        float z = acc + br[w];
        angles[b*16 + w] = tanhf(z) * 3.14159265358979323846f;
    }
}

// ---------------- VQC layer kernel ----------------
// index i (16b): wire w <-> bit 15-w (wire0 = MSB). chunk c = i>>14 (wires 0,1).
// Per layer: G4 = (RZ*RY on wires 0,1) + CNOT(0,1) applied as 4x4 cross-chunk mix in R1;
// rounds R1..R4 apply wires 2..15 1q + CNOT chain in 16-amp register blocks.
__device__ __forceinline__ int SWZ(int m){ return m ^ ((m>>5)&31); }

template<int M>
__device__ __forceinline__ void applyw(float2* amp, const float* gw){
    float c_ = gw[0], s_ = gw[1], cp_ = gw[2], sp_ = gw[3];
    #pragma unroll
    for (int v=0; v<16; ++v) if (!(v & M)){
        float2 a0 = amp[v], a1 = amp[v|M];
        float n0x = c_*a0.x - s_*a1.x, n0y = c_*a0.y - s_*a1.y;
        float n1x = s_*a0.x + c_*a1.x, n1y = s_*a0.y + c_*a1.y;
        amp[v]   = make_float2(n0x, n0y);
        amp[v|M] = make_float2(n1x*cp_ - n1y*sp_, n1x*sp_ + n1y*cp_);
    }
}
__device__ __forceinline__ void chain3(float2* amp){
    // CNOT ctrl bit3->tgt bit2 ; ctrl bit2->tgt bit1 ; ctrl bit1->tgt bit0 (free reg perms)
    cswap(amp[8],amp[12]); cswap(amp[9],amp[13]); cswap(amp[10],amp[14]); cswap(amp[11],amp[15]);
    cswap(amp[4],amp[6]);  cswap(amp[5],amp[7]);  cswap(amp[12],amp[14]); cswap(amp[13],amp[15]);
    cswap(amp[2],amp[3]);  cswap(amp[6],amp[7]);  cswap(amp[10],amp[11]); cswap(amp[14],amp[15]);
}
__device__ __forceinline__ void swap8u(float2* amp){
    #pragma unroll
    for (int v=0; v<8; ++v) cswap(amp[v], amp[v+8]);
}
__device__ __forceinline__ void dswap8(float2* amp, bool ct){
    #pragma unroll
    for (int v=0; v<8; ++v){
        float2 ta = amp[v], tb = amp[v+8];
        amp[v] = ct ? tb : ta; amp[v+8] = ct ? ta : tb;
    }
}

template<bool INIT, bool MEASURE>
__global__ __launch_bounds__(1024) void k_vqc(
        const float* __restrict__ wgt,      // [6][16][2]
        const float* __restrict__ angles,   // [64][16]
        const float2* __restrict__ sin_,
        float2* __restrict__ sout,
        float* __restrict__ qacc,
        int L){
    extern __shared__ float smem[];
    float* reL    = smem;                     // [16384]
    float* imL    = smem + 16384;             // [16384]
    float* gatesL = smem + 32768;             // [16][4] c,s,cosphi,sinphi
    float2* Atab  = (float2*)(smem + 32832);  // [256]  (INIT only)
    float2* Btab  = Atab + 256;               // [512]
    const int T  = threadIdx.x;
    const int bx = blockIdx.x;
    const int c  = bx >> 6;      // chunk (wires 0,1); blockIdx=c*64+b keeps sample on one XCD
    const int b  = bx & 63;

    if (T < 16){
        float th = wgt[(L*16 + T)*2 + 0];
        float ph = wgt[(L*16 + T)*2 + 1];
        float s_, c_, sp_, cp_;
        sincosf(0.5f*th, &s_, &c_);
        sincosf(ph, &sp_, &cp_);
        gatesL[T*4+0] = c_; gatesL[T*4+1] = s_;
        gatesL[T*4+2] = cp_; gatesL[T*4+3] = sp_;
    }
    if (INIT){
        // product state after encoding RY + layer0 1q; CNOT chain of layer0 = Gray map
        if (T < 256){
            int h = T, g = h ^ (h>>1);
            float2 p = make_float2(1.f, 0.f);
            #pragma unroll
            for (int w=0; w<8; ++w){
                float th = wgt[w*2+0], ph = wgt[w*2+1];
                float a  = angles[b*16 + w];
                float sb, cb; sincosf(0.5f*(a+th), &sb, &cb);
                float sp, cp; sincosf(ph, &sp, &cp);
                if ((g >> (7-w)) & 1) p = cmulf(p, make_float2(sb*cp, sb*sp));
                else { p.x *= cb; p.y *= cb; }
            }
            Atab[h] = p;
        } else if (T < 768){
            int l9 = T - 256, gl = (l9 ^ (l9>>1)) & 255;
            float2 p = make_float2(1.f, 0.f);
            #pragma unroll
            for (int w=8; w<16; ++w){
                float th = wgt[w*2+0], ph = wgt[w*2+1];
                float a  = angles[b*16 + w];
                float sb, cb; sincosf(0.5f*(a+th), &sb, &cb);
                float sp, cp; sincosf(ph, &sp, &cp);
                if ((gl >> (15-w)) & 1) p = cmulf(p, make_float2(sb*cp, sb*sp));
                else { p.x *= cb; p.y *= cb; }
            }
            Btab[l9] = p;
        }
    }
    __syncthreads();

    // G4 row for own chunk c: G[c][c'] = U0[c1][c1'] * U1[c0^c1][c0']
    float2 G4r[4];
    {
        float c0_=gatesL[0], s0_=gatesL[1], cp0=gatesL[2], sp0=gatesL[3];
        float c1_=gatesL[4], s1_=gatesL[5], cp1=gatesL[6], sp1=gatesL[7];
        float2 U0[2][2] = {{{c0_,0.f},{-s0_,0.f}},{{s0_*cp0,s0_*sp0},{c0_*cp0,c0_*sp0}}};
        float2 U1[2][2] = {{{c1_,0.f},{-s1_,0.f}},{{s1_*cp1,s1_*sp1},{c1_*cp1,c1_*sp1}}};
        int c1b = c>>1, c0b = c&1;
        #pragma unroll
        for (int cp=0; cp<4; ++cp)
            G4r[cp] = cmulf(U0[c1b][cp>>1], U1[c0b ^ c1b][cp & 1]);
    }

    float2 amp[16];
    // ---- R1: cross-chunk 4x4 mix, then wires 2..5 (v bits 3..0 = index bits 13..10) ----
    if (INIT){
        float2 Bv = Btab[T & 511];
        #pragma unroll
        for (int v=0; v<16; ++v){
            float2 acc = make_float2(0.f,0.f);
            #pragma unroll
            for (int cp=0; cp<4; ++cp){
                float2 Av = Atab[(cp<<6)|(v<<2)|(T>>8)];
                float2 gq = cmulf(G4r[cp], cmulf(Av, Bv));
                acc.x += gq.x; acc.y += gq.y;
            }
            amp[v] = acc;
        }
    } else {
        const float2* base = sin_ + ((size_t)b << 16);
        #pragma unroll
        for (int v=0; v<16; ++v){
            float2 acc = make_float2(0.f,0.f);
            #pragma unroll
            for (int cp=0; cp<4; ++cp){
                float2 q = base[(cp<<14)|(v<<10)|T];
                float2 gq = cmulf(G4r[cp], q);
                acc.x += gq.x; acc.y += gq.y;
            }
            amp[v] = acc;
        }
    }
    applyw<8>(amp, gatesL+2*4); applyw<4>(amp, gatesL+3*4);
    applyw<2>(amp, gatesL+4*4); applyw<1>(amp, gatesL+5*4);
    if (c & 1) swap8u(amp);      // CNOT(1,2): ctrl wire1 = chunk bit (wg-uniform)
    chain3(amp);                 // CNOT(2,3),(3,4),(4,5)
    #pragma unroll
    for (int v=0; v<16; ++v){
        int sm = SWZ((v<<10)|T);
        reL[sm] = amp[v].x; imL[sm] = amp[v].y;
    }
    __syncthreads();
    // ---- R2: wires 6..9 (bits 9..6) ----
    {
        int hi = (T>>6)<<10, lo = T & 63;
        #pragma unroll
        for (int v=0; v<16; ++v){
            int sm = SWZ(hi | (v<<6) | lo);
            amp[v] = make_float2(reL[sm], imL[sm]);
        }
        applyw<8>(amp, gatesL+6*4); applyw<4>(amp, gatesL+7*4);
        applyw<2>(amp, gatesL+8*4); applyw<1>(amp, gatesL+9*4);
        if ((T>>6)&1) swap8u(amp);   // CNOT(5,6): ctrl = T bit6 (wave-uniform)
        chain3(amp);                 // CNOT(6,7),(7,8),(8,9)
        #pragma unroll
        for (int v=0; v<16; ++v){
            int sm = SWZ(hi | (v<<6) | lo);
            reL[sm] = amp[v].x; imL[sm] = amp[v].y;
        }
    }
    __syncthreads();
    // ---- R3: wires 10..13 (bits 5..2) ----
    {
        int hi = (T>>2)<<6, lo = T & 3;
        #pragma unroll
        for (int v=0; v<16; ++v){
            int sm = SWZ(hi | (v<<2) | lo);
            amp[v] = make_float2(reL[sm], imL[sm]);
        }
        applyw<8>(amp, gatesL+10*4); applyw<4>(amp, gatesL+11*4);
        applyw<2>(amp, gatesL+12*4); applyw<1>(amp, gatesL+13*4);
        dswap8(amp, ((T>>2)&1) != 0);  // CNOT(9,10): ctrl = T bit2 (lane-divergent)
        chain3(amp);                   // CNOT(10,11),(11,12),(12,13)
        #pragma unroll
        for (int v=0; v<16; ++v){
            int sm = SWZ(hi | (v<<2) | lo);
            reL[sm] = amp[v].x; imL[sm] = amp[v].y;
        }
    }
    __syncthreads();
    // ---- R4: wires 14,15 (bits 1,0); bits 3,2 along for the ride ----
    {
        #pragma unroll
        for (int v=0; v<16; ++v){
            int sm = SWZ((T<<4)|v);
            amp[v] = make_float2(reL[sm], imL[sm]);
        }
        applyw<2>(amp, gatesL+14*4); applyw<1>(amp, gatesL+15*4);
        // CNOT(13,14): ctrl v bit2 -> swap (v,v|2) for v in {4,5,12,13}
        cswap(amp[4],amp[6]); cswap(amp[5],amp[7]); cswap(amp[12],amp[14]); cswap(amp[13],amp[15]);
        // CNOT(14,15): ctrl v bit1 -> swap (v,v|1) for v in {2,6,10,14}
        cswap(amp[2],amp[3]); cswap(amp[6],amp[7]); cswap(amp[10],amp[11]); cswap(amp[14],amp[15]);
        if (MEASURE){
            float ps = 0.f;
            #pragma unroll
            for (int v=0; v<16; ++v) ps += amp[v].x*amp[v].x + amp[v].y*amp[v].y;
            #pragma unroll
            for (int m=32;m>=1;m>>=1) ps += __shfl_xor(ps, m);
            __syncthreads();                 // all R4 LDS reads done before reuse
            if ((T & 63) == 0) reL[T>>6] = ps;
            __syncthreads();
            if (T == 0){
                float tot = 0.f;
                #pragma unroll
                for (int k=0;k<16;++k) tot += reL[k];
                float sgn = (c & 2) ? -1.f : 1.f;   // wire0 = chunk bit1
                atomicAdd(&qacc[b], sgn*tot);
            }
        } else {
            float4* po = (float4*)(sout + ((size_t)b<<16) + ((size_t)c<<14) + (T<<4));
            #pragma unroll
            for (int k=0;k<8;++k)
                po[k] = make_float4(amp[2*k].x, amp[2*k].y, amp[2*k+1].x, amp[2*k+1].y);
        }
    }
}

// ---------------- final sigmoid ----------------
__global__ void k_fin(const float* __restrict__ qacc, float* __restrict__ out){
    int i = threadIdx.x;
    if (i < 64) out[i] = 1.f/(1.f + expf(-qacc[i]));
}

extern "C" void kernel_launch(void* const* d_in, const int* in_sizes, int n_in,
                              void* d_out, int out_size, void* d_ws, size_t ws_size,
                              hipStream_t stream){
    (void)in_sizes; (void)n_in; (void)out_size; (void)ws_size;
    const float* x  = (const float*)d_in[0];
    const float* Wc = (const float*)d_in[1];
    const float* bc = (const float*)d_in[2];
    const float* Wr = (const float*)d_in[3];
    const float* br = (const float*)d_in[4];
    const float* wq = (const float*)d_in[5];
    float* ws     = (float*)d_ws;
    float* feat   = ws;
    float* angles = ws + 32768;
    float* qacc   = ws + 33792;
    float2* SA = (float2*)((char*)d_ws + ((size_t)4<<20));
    float2* SB = SA + ((size_t)64<<16);
    float* outF = (float*)d_out;

    const int dynG = 32832*4;           // 131328 B
    const int dynI = dynG + 768*8;      // 137472 B
    hipFuncSetAttribute(reinterpret_cast<const void*>(&k_vqc<true,false>),
                        hipFuncAttributeMaxDynamicSharedMemorySize, dynI);
    hipFuncSetAttribute(reinterpret_cast<const void*>(&k_vqc<false,false>),
                        hipFuncAttributeMaxDynamicSharedMemorySize, dynG);
    hipFuncSetAttribute(reinterpret_cast<const void*>(&k_vqc<false,true>),
                        hipFuncAttributeMaxDynamicSharedMemorySize, dynG);

    k_zero<<<133,256,0,stream>>>(ws);
    k_conv<<<64*28,256,0,stream>>>(x, Wc, bc, feat);
    k_red<<<64,1024,0,stream>>>(feat, Wr, br, angles);
    k_vqc<true ,false><<<256,1024,dynI,stream>>>(wq, angles, nullptr, SA, qacc, 1);
    k_vqc<false,false><<<256,1024,dynG,stream>>>(wq, angles, SA, SB, qacc, 2);
    k_vqc<false,false><<<256,1024,dynG,stream>>>(wq, angles, SB, SA, qacc, 3);
    k_vqc<false,false><<<256,1024,dynG,stream>>>(wq, angles, SA, SB, qacc, 4);
    k_vqc<false,true ><<<256,1024,dynG,stream>>>(wq, angles, SB, nullptr, qacc, 5);
    k_fin<<<1,64,0,stream>>>(qacc, outF);
}

// Round 2
// 219.062 us; speedup vs baseline: 1.9838x; 1.9838x over previous
//
#include <hip/hip_runtime.h>
#include <hip/hip_bf16.h>
#include <math.h>

// ws layout (floats): [0,32768) feat512; [32768,33792) angles; [33792,33856) qacc
// f16 state ping-pong at byte offset 4MB: SA, SB (each 64*65536*4B = 16.78MB)

typedef _Float16 h4 __attribute__((ext_vector_type(4)));
typedef _Float16 h8 __attribute__((ext_vector_type(8)));
typedef float f32x4 __attribute__((ext_vector_type(4)));

__device__ __forceinline__ float2 cmulf(float2 a, float2 b){
    return make_float2(a.x*b.x - a.y*b.y, a.x*b.y + a.y*b.x);
}
__device__ __forceinline__ void cswap(float2& a, float2& b){ float2 t=a; a=b; b=t; }
__device__ __forceinline__ unsigned packh2(float2 a){
    union{ _Float16 h[2]; unsigned u; } z;
    z.h[0] = (_Float16)a.x; z.h[1] = (_Float16)a.y; return z.u;
}
__device__ __forceinline__ float2 unpackh2(unsigned u){
    union{ unsigned u; _Float16 h[2]; } z; z.u = u;
    return make_float2((float)z.h[0], (float)z.h[1]);
}

// ---------------- zero small ws arrays ----------------
__global__ void k_zero(float* ws){
    int i = blockIdx.x*256 + threadIdx.x;
    if (i < 33856) ws[i] = 0.0f;
}

// ---------------- conv + relu + global-avg-pool via MFMA ----------------
// GEMM: out[pos][ch] = sum_k A[pos][k]*W[ch][k], k = c*16+r*4+cc (48, padded to 64).
// Block: 256 thr (4 waves), 112 positions (2 output rows) of one sample. Grid 64*28.
__global__ __launch_bounds__(256) void k_conv_mfma(const float* __restrict__ x,
            const float* __restrict__ Wc, const float* __restrict__ bc,
            float* __restrict__ feat){
    extern __shared__ _Float16 clds[];
    _Float16* Wl = clds;             // [512][56]
    _Float16* Al = clds + 512*56;    // [112][56]
    const int tid = threadIdx.x;
    const int b = blockIdx.x / 28, seg = blockIdx.x % 28;
    // stage W (512x48 f32 -> f16), row stride 56 (112B: 2-way banks, 16B aligned)
    for (int j = tid; j < 6144; j += 256){
        int o = j / 12, q = j - o*12;
        float4 w = ((const float4*)Wc)[j];
        h4 hv; hv[0]=(_Float16)w.x; hv[1]=(_Float16)w.y; hv[2]=(_Float16)w.z; hv[3]=(_Float16)w.w;
        *(h4*)&Wl[o*56 + q*4] = hv;
    }
    // stage A: 112 positions x 12 (c,r) float4 patch rows
    for (int idx = tid; idx < 1344; idx += 256){
        int cr = idx / 112, p = idx - cr*112;
        int cc = cr >> 2, r = cr & 3;
        int row2 = p / 56, ow = p - row2*56;
        int ih = (seg*2 + row2)*4 + r;
        float4 v = *(const float4*)&x[(((size_t)b*3 + cc)*224 + ih)*224 + ow*4];
        h4 hv; hv[0]=(_Float16)v.x; hv[1]=(_Float16)v.y; hv[2]=(_Float16)v.z; hv[3]=(_Float16)v.w;
        *(h4*)&Al[p*56 + cr*4] = hv;
    }
    __syncthreads();
    const int wv = tid >> 6, lane = tid & 63;
    const int col = lane & 15, kg = lane >> 4;
    const int n0 = wv * 128;
    const h8 hz = {0,0,0,0,0,0,0,0};
    // B fragments in registers: 8 N-tiles x 2 k-steps
    h8 Bf[8], Bf2[8];
    float bias[8], pool[8];
    #pragma unroll
    for (int nt=0; nt<8; ++nt){
        int o = n0 + nt*16 + col;
        Bf[nt]  = *(const h8*)&Wl[o*56 + kg*8];
        Bf2[nt] = (kg < 2) ? *(const h8*)&Wl[o*56 + 32 + kg*8] : hz;
        bias[nt] = bc[o];
        pool[nt] = 0.f;
    }
    #pragma unroll
    for (int mt=0; mt<7; ++mt){
        int arow = mt*16 + col;
        h8 Af  = *(const h8*)&Al[arow*56 + kg*8];
        h8 Af2 = (kg < 2) ? *(const h8*)&Al[arow*56 + 32 + kg*8] : hz;
        #pragma unroll
        for (int nt=0; nt<8; ++nt){
            f32x4 acc = {0.f,0.f,0.f,0.f};
            acc = __builtin_amdgcn_mfma_f32_16x16x32_f16(Af,  Bf[nt],  acc, 0,0,0);
            acc = __builtin_amdgcn_mfma_f32_16x16x32_f16(Af2, Bf2[nt], acc, 0,0,0);
            #pragma unroll
            for (int j=0;j<4;++j) pool[nt] += fmaxf(acc[j] + bias[nt], 0.f);
        }
    }
    #pragma unroll
    for (int nt=0; nt<8; ++nt){
        pool[nt] += __shfl_xor(pool[nt], 16);
        pool[nt] += __shfl_xor(pool[nt], 32);
    }
    if (lane < 16){
        #pragma unroll
        for (int nt=0; nt<8; ++nt)
            atomicAdd(&feat[b*512 + n0 + nt*16 + lane], pool[nt]);
    }
}

// ---------------- reducer: tanh(feat/3136 @ Wr^T + br) * pi ----------------
__global__ __launch_bounds__(1024) void k_red(const float* __restrict__ feat,
        const float* __restrict__ Wr, const float* __restrict__ br,
        float* __restrict__ angles){
    int b = blockIdx.x;
    int tid = threadIdx.x;
    int w = tid >> 6, l = tid & 63;
    float acc = 0.f;
    #pragma unroll
    for (int k=0;k<8;++k){
        int idx = l + 64*k;
        acc += (feat[b*512 + idx] * (1.0f/3136.0f)) * Wr[w*512 + idx];
    }
    #pragma unroll
    for (int m=32;m>=1;m>>=1) acc += __shfl_xor(acc, m);
    if (l == 0){
        float z = acc + br[w];
        angles[b*16 + w] = tanhf(z) * 3.14159265358979323846f;
    }
}

// ---------------- VQC layer kernel (f16 state) ----------------
// global index i[15:0], wire w <-> bit 15-w. chunk c = i[15:14] (wires 0,1).
// m = i[13:0]. Rounds: R1 regs {m13,m12,m1,m0} (wires 2,3,14,15),
// R2 {m11..m8} (w4..7), R3 {m7..m4} (w8..11), R4 {m3..m0} (w12..15).
__device__ __forceinline__ int SWZ(int m){ return m ^ ((m>>5)&31); }

template<int M>
__device__ __forceinline__ void applyw(float2* amp, const float* gw){
    float c_ = gw[0], s_ = gw[1], cp_ = gw[2], sp_ = gw[3];
    #pragma unroll
    for (int v=0; v<16; ++v) if (!(v & M)){
        float2 a0 = amp[v], a1 = amp[v|M];
        float n0x = c_*a0.x - s_*a1.x, n0y = c_*a0.y - s_*a1.y;
        float n1x = s_*a0.x + c_*a1.x, n1y = s_*a0.y + c_*a1.y;
        amp[v]   = make_float2(n0x, n0y);
        amp[v|M] = make_float2(n1x*cp_ - n1y*sp_, n1x*sp_ + n1y*cp_);
    }
}
__device__ __forceinline__ void chain3(float2* amp){
    // CN(bit3->bit2), CN(bit2->bit1), CN(bit1->bit0)
    cswap(amp[8],amp[12]); cswap(amp[9],amp[13]); cswap(amp[10],amp[14]); cswap(amp[11],amp[15]);
    cswap(amp[4],amp[6]);  cswap(amp[5],amp[7]);  cswap(amp[12],amp[14]); cswap(amp[13],amp[15]);
    cswap(amp[2],amp[3]);  cswap(amp[6],amp[7]);  cswap(amp[10],amp[11]); cswap(amp[14],amp[15]);
}
__device__ __forceinline__ void swap8u(float2* amp){   // flip bit3
    #pragma unroll
    for (int v=0; v<8; ++v) cswap(amp[v], amp[v+8]);
}

template<bool INIT, bool MEASURE>
__global__ __launch_bounds__(1024) void k_vqc(
        const float* __restrict__ wgt,      // [6][16][2]
        const float* __restrict__ angles,   // [64][16]
        const unsigned* __restrict__ sin_,  // f16x2 per amp
        unsigned* __restrict__ sout,
        float* __restrict__ qacc,
        int L){
    extern __shared__ float smem[];
    float* reL    = smem;                     // [16384]
    float* imL    = smem + 16384;             // [16384]
    float* gatesL = smem + 32768;             // [16][4] c,s,cosphi,sinphi
    float2* Atab  = (float2*)(smem + 32832);  // [256]  (INIT only)
    float2* Btab  = Atab + 256;               // [512]
    const int T  = threadIdx.x;
    const int c  = blockIdx.x >> 6;   // chunk; blockIdx=c*64+b keeps sample on one XCD
    const int b  = blockIdx.x & 63;

    if (T < 16){
        float th = wgt[(L*16 + T)*2 + 0];
        float ph = wgt[(L*16 + T)*2 + 1];
        float s_, c_, sp_, cp_;
        sincosf(0.5f*th, &s_, &c_);
        sincosf(ph, &sp_, &cp_);
        gatesL[T*4+0] = c_; gatesL[T*4+1] = s_;
        gatesL[T*4+2] = cp_; gatesL[T*4+3] = sp_;
    }
    if (INIT){
        // product state after encoding RY + layer0 1q; layer0 CNOT chain = Gray map
        if (T < 256){
            int h = T, g = h ^ (h>>1);
            float2 p = make_float2(1.f, 0.f);
            #pragma unroll
            for (int w=0; w<8; ++w){
                float th = wgt[w*2+0], ph = wgt[w*2+1];
                float a  = angles[b*16 + w];
                float sb, cb; sincosf(0.5f*(a+th), &sb, &cb);
                float sp, cp; sincosf(ph, &sp, &cp);
                if ((g >> (7-w)) & 1) p = cmulf(p, make_float2(sb*cp, sb*sp));
                else { p.x *= cb; p.y *= cb; }
            }
            Atab[h] = p;
        } else if (T < 768){
            int l9 = T - 256, gl = (l9 ^ (l9>>1)) & 255;
            float2 p = make_float2(1.f, 0.f);
            #pragma unroll
            for (int w=8; w<16; ++w){
                float th = wgt[w*2+0], ph = wgt[w*2+1];
                float a  = angles[b*16 + w];
                float sb, cb; sincosf(0.5f*(a+th), &sb, &cb);
                float sp, cp; sincosf(ph, &sp, &cp);
                if ((gl >> (15-w)) & 1) p = cmulf(p, make_float2(sb*cp, sb*sp));
                else { p.x *= cb; p.y *= cb; }
            }
            Btab[l9] = p;
        }
    }
    __syncthreads();

    // G4 row for own chunk c: wires 0,1 RY*RZ + CNOT(0,1)
    float2 G4r[4];
    {
        float c0_=gatesL[0], s0_=gatesL[1], cp0=gatesL[2], sp0=gatesL[3];
        float c1_=gatesL[4], s1_=gatesL[5], cp1=gatesL[6], sp1=gatesL[7];
        float2 U0[2][2] = {{{c0_,0.f},{-s0_,0.f}},{{s0_*cp0,s0_*sp0},{c0_*cp0,c0_*sp0}}};
        float2 U1[2][2] = {{{c1_,0.f},{-s1_,0.f}},{{s1_*cp1,s1_*sp1},{c1_*cp1,c1_*sp1}}};
        int c1b = c>>1, c0b = c&1;
        #pragma unroll
        for (int cp=0; cp<4; ++cp)
            G4r[cp] = cmulf(U0[c1b][cp>>1], U1[c0b ^ c1b][cp & 1]);
    }

    float2 amp[16];   // amp[(v2<<2)|u]: i = (c<<14)|(v2<<12)|(T<<2)|u
    if (INIT){
        float2 Bt[4];
        #pragma unroll
        for (int u=0;u<4;++u) Bt[u] = Btab[((T&63)<<2)|u];
        #pragma unroll
        for (int v2=0; v2<4; ++v2){
            int ihi = (v2<<4) | ((T>>6)&15);
            float2 a[4] = {{0,0},{0,0},{0,0},{0,0}};
            #pragma unroll
            for (int cp=0; cp<4; ++cp){
                float2 Ag = cmulf(G4r[cp], Atab[(cp<<6)|ihi]);
                #pragma unroll
                for (int u=0;u<4;++u){
                    float2 t = cmulf(Ag, Bt[u]);
                    a[u].x += t.x; a[u].y += t.y;
                }
            }
            #pragma unroll
            for (int u=0;u<4;++u) amp[(v2<<2)|u] = a[u];
        }
    } else {
        const unsigned* base = sin_ + ((size_t)b << 16);
        #pragma unroll
        for (int v2=0; v2<4; ++v2){
            float2 a[4] = {{0,0},{0,0},{0,0},{0,0}};
            #pragma unroll
            for (int cp=0; cp<4; ++cp){
                uint4 q = *(const uint4*)(base + ((cp<<14)|(v2<<12)|(T<<2)));
                float2 g = G4r[cp];
                float2 t0=unpackh2(q.x), t1=unpackh2(q.y), t2=unpackh2(q.z), t3=unpackh2(q.w);
                a[0].x += g.x*t0.x - g.y*t0.y; a[0].y += g.x*t0.y + g.y*t0.x;
                a[1].x += g.x*t1.x - g.y*t1.y; a[1].y += g.x*t1.y + g.y*t1.x;
                a[2].x += g.x*t2.x - g.y*t2.y; a[2].y += g.x*t2.y + g.y*t2.x;
                a[3].x += g.x*t3.x - g.y*t3.y; a[3].y += g.x*t3.y + g.y*t3.x;
            }
            #pragma unroll
            for (int u=0;u<4;++u) amp[(v2<<2)|u] = a[u];
        }
    }
    // R1 gates: wires 2(bit3),3(bit2),14(bit1),15(bit0)
    applyw<8>(amp, gatesL+2*4);
    applyw<4>(amp, gatesL+3*4);
    applyw<2>(amp, gatesL+14*4);   // RY/RZ(14) hoisted (commutes up to CN(13,14))
    applyw<1>(amp, gatesL+15*4);   // RY/RZ(15) hoisted
    if (c & 1) swap8u(amp);        // CN(1,2): ctrl wire1 = c bit0 (wg-uniform)
    cswap(amp[8],amp[12]); cswap(amp[9],amp[13]); cswap(amp[10],amp[14]); cswap(amp[11],amp[15]); // CN(2,3)
    #pragma unroll
    for (int r=0;r<16;++r){
        int sm = SWZ(((r>>2)<<12) | (T<<2) | (r&3));
        reL[sm] = amp[r].x; imL[sm] = amp[r].y;
    }
    __syncthreads();
    // ---- R2: wires 4..7 (m11..m8); thread: m13..12 = T>>8, m7..0 = T&255 ----
    {
        int hi = (T>>8)<<12, lo = T & 255;
        #pragma unroll
        for (int r=0;r<16;++r){
            int sm = SWZ(hi | (r<<8) | lo);
            amp[r] = make_float2(reL[sm], imL[sm]);
        }
        applyw<8>(amp, gatesL+4*4); applyw<4>(amp, gatesL+5*4);
        applyw<2>(amp, gatesL+6*4); applyw<1>(amp, gatesL+7*4);
        if ((T>>8)&1) swap8u(amp);   // CN(3,4): ctrl m12 (thread-uniform)
        chain3(amp);                 // CN(4,5),(5,6),(6,7)
        #pragma unroll
        for (int r=0;r<16;++r){
            int sm = SWZ(hi | (r<<8) | lo);
            reL[sm] = amp[r].x; imL[sm] = amp[r].y;
        }
    }
    __syncthreads();
    // ---- R3: wires 8..11 (m7..m4); thread: m13..8 = T>>4, m3..0 = T&15 ----
    {
        int hi = (T>>4)<<8, lo = T & 15;
        #pragma unroll
        for (int r=0;r<16;++r){
            int sm = SWZ(hi | (r<<4) | lo);
            amp[r] = make_float2(reL[sm], imL[sm]);
        }
        applyw<8>(amp, gatesL+8*4);  applyw<4>(amp, gatesL+9*4);
        applyw<2>(amp, gatesL+10*4); applyw<1>(amp, gatesL+11*4);
        if ((T>>4)&1) swap8u(amp);   // CN(7,8): ctrl m8 (thread-uniform)
        chain3(amp);                 // CN(8,9),(9,10),(10,11)
        #pragma unroll
        for (int r=0;r<16;++r){
            int sm = SWZ(hi | (r<<4) | lo);
            reL[sm] = amp[r].x; imL[sm] = amp[r].y;
        }
    }
    __syncthreads();
    // ---- R4: wires 12..15 (m3..m0); thread: m13..4 = T ----
    {
        #pragma unroll
        for (int r=0;r<16;++r){
            int sm = SWZ((T<<4) | r);
            amp[r] = make_float2(reL[sm], imL[sm]);
        }
        applyw<8>(amp, gatesL+12*4); applyw<4>(amp, gatesL+13*4);
        if (T & 1) swap8u(amp);      // CN(11,12): ctrl m4 = T bit0 (thread-uniform)
        chain3(amp);                 // CN(12,13),(13,14),(14,15)
        if (MEASURE){
            float ps = 0.f;
            #pragma unroll
            for (int r=0;r<16;++r) ps += amp[r].x*amp[r].x + amp[r].y*amp[r].y;
            #pragma unroll
            for (int m=32;m>=1;m>>=1) ps += __shfl_xor(ps, m);
            __syncthreads();
            if ((T & 63) == 0) reL[T>>6] = ps;
            __syncthreads();
            if (T == 0){
                float tot = 0.f;
                #pragma unroll
                for (int k=0;k<16;++k) tot += reL[k];
                float sgn = (c & 2) ? -1.f : 1.f;   // wire0 = c bit1
                atomicAdd(&qacc[b], sgn*tot);
            }
        } else {
            unsigned* po = sout + (((size_t)b<<16) | (c<<14) | (T<<4));
            #pragma unroll
            for (int k2=0;k2<4;++k2){
                uint4 qq;
                qq.x = packh2(amp[k2*4+0]); qq.y = packh2(amp[k2*4+1]);
                qq.z = packh2(amp[k2*4+2]); qq.w = packh2(amp[k2*4+3]);
                *(uint4*)(po + k2*4) = qq;
            }
        }
    }
}

// ---------------- final sigmoid ----------------
__global__ void k_fin(const float* __restrict__ qacc, float* __restrict__ out){
    int i = threadIdx.x;
    if (i < 64) out[i] = 1.f/(1.f + expf(-qacc[i]));
}

extern "C" void kernel_launch(void* const* d_in, const int* in_sizes, int n_in,
                              void* d_out, int out_size, void* d_ws, size_t ws_size,
                              hipStream_t stream){
    (void)in_sizes; (void)n_in; (void)out_size; (void)ws_size;
    const float* x  = (const float*)d_in[0];
    const float* Wc = (const float*)d_in[1];
    const float* bc = (const float*)d_in[2];
    const float* Wr = (const float*)d_in[3];
    const float* br = (const float*)d_in[4];
    const float* wq = (const float*)d_in[5];
    float* ws     = (float*)d_ws;
    float* feat   = ws;
    float* angles = ws + 32768;
    float* qacc   = ws + 33792;
    unsigned* SA = (unsigned*)((char*)d_ws + ((size_t)4<<20));
    unsigned* SB = SA + ((size_t)64<<16);
    float* outF = (float*)d_out;

    const int dynG = 32832*4;            // 131328 B
    const int dynI = dynG + 768*8;       // 137472 B
    const int dynC = (512*56 + 112*56)*2; // 69888 B
    hipFuncSetAttribute(reinterpret_cast<const void*>(&k_conv_mfma),
                        hipFuncAttributeMaxDynamicSharedMemorySize, dynC);
    hipFuncSetAttribute(reinterpret_cast<const void*>(&k_vqc<true,false>),
                        hipFuncAttributeMaxDynamicSharedMemorySize, dynI);
    hipFuncSetAttribute(reinterpret_cast<const void*>(&k_vqc<false,false>),
                        hipFuncAttributeMaxDynamicSharedMemorySize, dynG);
    hipFuncSetAttribute(reinterpret_cast<const void*>(&k_vqc<false,true>),
                        hipFuncAttributeMaxDynamicSharedMemorySize, dynG);

    k_zero<<<133,256,0,stream>>>(ws);
    k_conv_mfma<<<64*28,256,dynC,stream>>>(x, Wc, bc, feat);
    k_red<<<64,1024,0,stream>>>(feat, Wr, br, angles);
    k_vqc<true ,false><<<256,1024,dynI,stream>>>(wq, angles, nullptr, SA, qacc, 1);
    k_vqc<false,false><<<256,1024,dynG,stream>>>(wq, angles, SA, SB, qacc, 2);
    k_vqc<false,false><<<256,1024,dynG,stream>>>(wq, angles, SB, SA, qacc, 3);
    k_vqc<false,false><<<256,1024,dynG,stream>>>(wq, angles, SA, SB, qacc, 4);
    k_vqc<false,true ><<<256,1024,dynG,stream>>>(wq, angles, SB, SA, qacc, 5);
    k_fin<<<1,64,0,stream>>>(qacc, outF);
}

// Round 3
// 179.700 us; speedup vs baseline: 2.4183x; 1.2190x over previous
//
#include <hip/hip_runtime.h>
#include <hip/hip_bf16.h>
#include <math.h>

// ws layout (floats): [0,32768) feat512; [32768,33792) angles; [33792,33856) qacc
// Wh f16 [512][64] at byte offset 1MB (64KB)
// f16 state ping-pong at byte offset 4MB: SA, SB (each 64*65536*4B = 16.78MB)

typedef _Float16 h4 __attribute__((ext_vector_type(4)));
typedef _Float16 h8 __attribute__((ext_vector_type(8)));
typedef float f32x4 __attribute__((ext_vector_type(4)));

__device__ __forceinline__ float2 cmulf(float2 a, float2 b){
    return make_float2(a.x*b.x - a.y*b.y, a.x*b.y + a.y*b.x);
}
__device__ __forceinline__ void cswap(float2& a, float2& b){ float2 t=a; a=b; b=t; }
__device__ __forceinline__ unsigned packh2(float2 a){
    union{ _Float16 h[2]; unsigned u; } z;
    z.h[0] = (_Float16)a.x; z.h[1] = (_Float16)a.y; return z.u;
}
__device__ __forceinline__ float2 unpackh2(unsigned u){
    union{ unsigned u; _Float16 h[2]; } z; z.u = u;
    return make_float2((float)z.h[0], (float)z.h[1]);
}

// ---------------- zero small ws arrays ----------------
__global__ void k_zero(float* ws){
    int i = blockIdx.x*256 + threadIdx.x;
    if (i < 33856) ws[i] = 0.0f;
}

// ---------------- W f32 -> f16, K padded 48->64 with zeros ----------------
__global__ void k_prep(const float* __restrict__ Wc, _Float16* __restrict__ Wh){
    int i = blockIdx.x*256 + threadIdx.x;   // 32768 = 512*64
    int ch = i >> 6, k = i & 63;
    Wh[i] = (k < 48) ? (_Float16)Wc[ch*48 + k] : (_Float16)0.f;
}

// ---------------- conv + relu + global-avg-pool via MFMA ----------------
// GEMM: out[pos][ch] = sum_k A[pos][k]*Wh[ch][k], k = cc*16+r*4+c4 (48, zero-pad 64).
// Block: 512 thr (8 waves), 224 positions (4 output rows) of one sample. Grid 64*14.
// Wave wv owns 4 N-tiles (64 channels); A staged in LDS [224][72] f16.
__global__ __launch_bounds__(512) void k_conv_mfma(const float* __restrict__ x,
            const _Float16* __restrict__ Wh, const float* __restrict__ bc,
            float* __restrict__ feat){
    extern __shared__ _Float16 Al[];   // [224][72]  (stride 144B: 16B-aligned, 4-bank step)
    const int tid = threadIdx.x;
    const int b = blockIdx.x / 14, seg = blockIdx.x % 14;
    // stage A: 224 positions x 12 (cc,r) float4 patch rows
    for (int idx = tid; idx < 2688; idx += 512){
        int cr = idx / 224, p = idx - cr*224;
        int cc = cr >> 2, r = cr & 3;
        int ro = p / 56, ow = p - ro*56;
        int ih = (seg*4 + ro)*4 + r;
        float4 v = *(const float4*)&x[(((size_t)b*3 + cc)*224 + ih)*224 + ow*4];
        h4 hv; hv[0]=(_Float16)v.x; hv[1]=(_Float16)v.y; hv[2]=(_Float16)v.z; hv[3]=(_Float16)v.w;
        *(h4*)&Al[p*72 + cr*4] = hv;
    }
    // zero-pad k = 48..63
    for (int idx = tid; idx < 896; idx += 512){
        int p = idx >> 2, j = idx & 3;
        *(h4*)&Al[p*72 + 48 + j*4] = (h4){0,0,0,0};
    }
    __syncthreads();
    const int wv = tid >> 6, lane = tid & 63;
    const int col = lane & 15, kg = lane >> 4;
    const int n0 = wv * 64;
    h8 Bf[4], Bf2[4];
    float bias[4], pool[4];
    #pragma unroll
    for (int nt=0; nt<4; ++nt){
        int ch = n0 + nt*16 + col;
        Bf[nt]  = *(const h8*)&Wh[ch*64 + kg*8];
        Bf2[nt] = *(const h8*)&Wh[ch*64 + 32 + kg*8];
        bias[nt] = bc[ch];
        pool[nt] = 0.f;
    }
    #pragma unroll 2
    for (int mt=0; mt<14; ++mt){
        const _Float16* ar = &Al[(mt*16 + col)*72];
        h8 Af  = *(const h8*)&ar[kg*8];
        h8 Af2 = *(const h8*)&ar[32 + kg*8];
        #pragma unroll
        for (int nt=0; nt<4; ++nt){
            f32x4 acc = {0.f,0.f,0.f,0.f};
            acc = __builtin_amdgcn_mfma_f32_16x16x32_f16(Af,  Bf[nt],  acc, 0,0,0);
            acc = __builtin_amdgcn_mfma_f32_16x16x32_f16(Af2, Bf2[nt], acc, 0,0,0);
            #pragma unroll
            for (int j=0;j<4;++j) pool[nt] += fmaxf(acc[j] + bias[nt], 0.f);
        }
    }
    #pragma unroll
    for (int nt=0; nt<4; ++nt){
        pool[nt] += __shfl_xor(pool[nt], 16);
        pool[nt] += __shfl_xor(pool[nt], 32);
    }
    if (lane < 16){
        #pragma unroll
        for (int nt=0; nt<4; ++nt)
            atomicAdd(&feat[b*512 + n0 + nt*16 + lane], pool[nt]);
    }
}

// ---------------- reducer: tanh(feat/3136 @ Wr^T + br) * pi ----------------
__global__ __launch_bounds__(1024) void k_red(const float* __restrict__ feat,
        const float* __restrict__ Wr, const float* __restrict__ br,
        float* __restrict__ angles){
    int b = blockIdx.x;
    int tid = threadIdx.x;
    int w = tid >> 6, l = tid & 63;
    float acc = 0.f;
    #pragma unroll
    for (int k=0;k<8;++k){
        int idx = l + 64*k;
        acc += (feat[b*512 + idx] * (1.0f/3136.0f)) * Wr[w*512 + idx];
    }
    #pragma unroll
    for (int m=32;m>=1;m>>=1) acc += __shfl_xor(acc, m);
    if (l == 0){
        float z = acc + br[w];
        angles[b*16 + w] = tanhf(z) * 3.14159265358979323846f;
    }
}

// ---------------- VQC layer kernel (f16 state) ----------------
// global index i[15:0], wire w <-> bit 15-w. chunk c = i[15:14] (wires 0,1).
// m = i[13:0]. Rounds: R1 regs {m13,m12,m1,m0} (wires 2,3,14,15),
// R2 {m11..m8} (w4..7), R3 {m7..m4} (w8..11), R4 {m3..m0} (w12..15).
__device__ __forceinline__ int SWZ(int m){ return m ^ ((m>>5)&31); }

template<int M>
__device__ __forceinline__ void applyw(float2* amp, const float* gw){
    float c_ = gw[0], s_ = gw[1], cp_ = gw[2], sp_ = gw[3];
    #pragma unroll
    for (int v=0; v<16; ++v) if (!(v & M)){
        float2 a0 = amp[v], a1 = amp[v|M];
        float n0x = c_*a0.x - s_*a1.x, n0y = c_*a0.y - s_*a1.y;
        float n1x = s_*a0.x + c_*a1.x, n1y = s_*a0.y + c_*a1.y;
        amp[v]   = make_float2(n0x, n0y);
        amp[v|M] = make_float2(n1x*cp_ - n1y*sp_, n1x*sp_ + n1y*cp_);
    }
}
__device__ __forceinline__ void chain3(float2* amp){
    // CN(bit3->bit2), CN(bit2->bit1), CN(bit1->bit0)
    cswap(amp[8],amp[12]); cswap(amp[9],amp[13]); cswap(amp[10],amp[14]); cswap(amp[11],amp[15]);
    cswap(amp[4],amp[6]);  cswap(amp[5],amp[7]);  cswap(amp[12],amp[14]); cswap(amp[13],amp[15]);
    cswap(amp[2],amp[3]);  cswap(amp[6],amp[7]);  cswap(amp[10],amp[11]); cswap(amp[14],amp[15]);
}
__device__ __forceinline__ void swap8u(float2* amp){   // flip bit3
    #pragma unroll
    for (int v=0; v<8; ++v) cswap(amp[v], amp[v+8]);
}

template<bool INIT, bool MEASURE>
__global__ __launch_bounds__(1024) void k_vqc(
        const float* __restrict__ wgt,      // [6][16][2]
        const float* __restrict__ angles,   // [64][16]
        const unsigned* __restrict__ sin_,  // f16x2 per amp
        unsigned* __restrict__ sout,
        float* __restrict__ qacc,
        int L){
    extern __shared__ float smem[];
    float* reL    = smem;                     // [16384]
    float* imL    = smem + 16384;             // [16384]
    float* gatesL = smem + 32768;             // [16][4] c,s,cosphi,sinphi
    float2* Atab  = (float2*)(smem + 32832);  // [256]  (INIT only)
    float2* Btab  = Atab + 256;               // [512]
    const int T  = threadIdx.x;
    const int c  = blockIdx.x >> 6;   // chunk; blockIdx=c*64+b keeps sample on one XCD
    const int b  = blockIdx.x & 63;

    if (T < 16){
        float th = wgt[(L*16 + T)*2 + 0];
        float ph = wgt[(L*16 + T)*2 + 1];
        float s_, c_, sp_, cp_;
        sincosf(0.5f*th, &s_, &c_);
        sincosf(ph, &sp_, &cp_);
        gatesL[T*4+0] = c_; gatesL[T*4+1] = s_;
        gatesL[T*4+2] = cp_; gatesL[T*4+3] = sp_;
    }
    if (INIT){
        // product state after encoding RY + layer0 1q; layer0 CNOT chain = Gray map
        if (T < 256){
            int h = T, g = h ^ (h>>1);
            float2 p = make_float2(1.f, 0.f);
            #pragma unroll
            for (int w=0; w<8; ++w){
                float th = wgt[w*2+0], ph = wgt[w*2+1];
                float a  = angles[b*16 + w];
                float sb, cb; sincosf(0.5f*(a+th), &sb, &cb);
                float sp, cp; sincosf(ph, &sp, &cp);
                if ((g >> (7-w)) & 1) p = cmulf(p, make_float2(sb*cp, sb*sp));
                else { p.x *= cb; p.y *= cb; }
            }
            Atab[h] = p;
        } else if (T < 768){
            int l9 = T - 256, gl = (l9 ^ (l9>>1)) & 255;
            float2 p = make_float2(1.f, 0.f);
            #pragma unroll
            for (int w=8; w<16; ++w){
                float th = wgt[w*2+0], ph = wgt[w*2+1];
                float a  = angles[b*16 + w];
                float sb, cb; sincosf(0.5f*(a+th), &sb, &cb);
                float sp, cp; sincosf(ph, &sp, &cp);
                if ((gl >> (15-w)) & 1) p = cmulf(p, make_float2(sb*cp, sb*sp));
                else { p.x *= cb; p.y *= cb; }
            }
            Btab[l9] = p;
        }
    }
    __syncthreads();

    // G4 row for own chunk c: wires 0,1 RY*RZ + CNOT(0,1)
    float2 G4r[4];
    {
        float c0_=gatesL[0], s0_=gatesL[1], cp0=gatesL[2], sp0=gatesL[3];
        float c1_=gatesL[4], s1_=gatesL[5], cp1=gatesL[6], sp1=gatesL[7];
        float2 U0[2][2] = {{{c0_,0.f},{-s0_,0.f}},{{s0_*cp0,s0_*sp0},{c0_*cp0,c0_*sp0}}};
        float2 U1[2][2] = {{{c1_,0.f},{-s1_,0.f}},{{s1_*cp1,s1_*sp1},{c1_*cp1,c1_*sp1}}};
        int c1b = c>>1, c0b = c&1;
        #pragma unroll
        for (int cp=0; cp<4; ++cp)
            G4r[cp] = cmulf(U0[c1b][cp>>1], U1[c0b ^ c1b][cp & 1]);
    }

    float2 amp[16];   // amp[(v2<<2)|u]: i = (c<<14)|(v2<<12)|(T<<2)|u
    if (INIT){
        float2 Bt[4];
        #pragma unroll
        for (int u=0;u<4;++u) Bt[u] = Btab[((T&63)<<2)|u];
        #pragma unroll
        for (int v2=0; v2<4; ++v2){
            int ihi = (v2<<4) | ((T>>6)&15);
            float2 a[4] = {{0,0},{0,0},{0,0},{0,0}};
            #pragma unroll
            for (int cp=0; cp<4; ++cp){
                float2 Ag = cmulf(G4r[cp], Atab[(cp<<6)|ihi]);
                #pragma unroll
                for (int u=0;u<4;++u){
                    float2 t = cmulf(Ag, Bt[u]);
                    a[u].x += t.x; a[u].y += t.y;
                }
            }
            #pragma unroll
            for (int u=0;u<4;++u) amp[(v2<<2)|u] = a[u];
        }
    } else {
        const unsigned* base = sin_ + ((size_t)b << 16);
        #pragma unroll
        for (int v2=0; v2<4; ++v2){
            float2 a[4] = {{0,0},{0,0},{0,0},{0,0}};
            #pragma unroll
            for (int cp=0; cp<4; ++cp){
                uint4 q = *(const uint4*)(base + ((cp<<14)|(v2<<12)|(T<<2)));
                float2 g = G4r[cp];
                float2 t0=unpackh2(q.x), t1=unpackh2(q.y), t2=unpackh2(q.z), t3=unpackh2(q.w);
                a[0].x += g.x*t0.x - g.y*t0.y; a[0].y += g.x*t0.y + g.y*t0.x;
                a[1].x += g.x*t1.x - g.y*t1.y; a[1].y += g.x*t1.y + g.y*t1.x;
                a[2].x += g.x*t2.x - g.y*t2.y; a[2].y += g.x*t2.y + g.y*t2.x;
                a[3].x += g.x*t3.x - g.y*t3.y; a[3].y += g.x*t3.y + g.y*t3.x;
            }
            #pragma unroll
            for (int u=0;u<4;++u) amp[(v2<<2)|u] = a[u];
        }
    }
    // R1 gates: wires 2(bit3),3(bit2),14(bit1),15(bit0)
    applyw<8>(amp, gatesL+2*4);
    applyw<4>(amp, gatesL+3*4);
    applyw<2>(amp, gatesL+14*4);   // RY/RZ(14) hoisted (commutes up to CN(13,14))
    applyw<1>(amp, gatesL+15*4);   // RY/RZ(15) hoisted
    if (c & 1) swap8u(amp);        // CN(1,2): ctrl wire1 = c bit0 (wg-uniform)
    cswap(amp[8],amp[12]); cswap(amp[9],amp[13]); cswap(amp[10],amp[14]); cswap(amp[11],amp[15]); // CN(2,3)
    #pragma unroll
    for (int r=0;r<16;++r){
        int sm = SWZ(((r>>2)<<12) | (T<<2) | (r&3));
        reL[sm] = amp[r].x; imL[sm] = amp[r].y;
    }
    __syncthreads();
    // ---- R2: wires 4..7 (m11..m8); thread: m13..12 = T>>8, m7..0 = T&255 ----
    {
        int hi = (T>>8)<<12, lo = T & 255;
        #pragma unroll
        for (int r=0;r<16;++r){
            int sm = SWZ(hi | (r<<8) | lo);
            amp[r] = make_float2(reL[sm], imL[sm]);
        }
        applyw<8>(amp, gatesL+4*4); applyw<4>(amp, gatesL+5*4);
        applyw<2>(amp, gatesL+6*4); applyw<1>(amp, gatesL+7*4);
        if ((T>>8)&1) swap8u(amp);   // CN(3,4): ctrl m12 (thread-uniform)
        chain3(amp);                 // CN(4,5),(5,6),(6,7)
        #pragma unroll
        for (int r=0;r<16;++r){
            int sm = SWZ(hi | (r<<8) | lo);
            reL[sm] = amp[r].x; imL[sm] = amp[r].y;
        }
    }
    __syncthreads();
    // ---- R3: wires 8..11 (m7..m4); thread: m13..8 = T>>4, m3..0 = T&15 ----
    {
        int hi = (T>>4)<<8, lo = T & 15;
        #pragma unroll
        for (int r=0;r<16;++r){
            int sm = SWZ(hi | (r<<4) | lo);
            amp[r] = make_float2(reL[sm], imL[sm]);
        }
        applyw<8>(amp, gatesL+8*4);  applyw<4>(amp, gatesL+9*4);
        applyw<2>(amp, gatesL+10*4); applyw<1>(amp, gatesL+11*4);
        if ((T>>4)&1) swap8u(amp);   // CN(7,8): ctrl m8 (thread-uniform)
        chain3(amp);                 // CN(8,9),(9,10),(10,11)
        #pragma unroll
        for (int r=0;r<16;++r){
            int sm = SWZ(hi | (r<<4) | lo);
            reL[sm] = amp[r].x; imL[sm] = amp[r].y;
        }
    }
    __syncthreads();
    // ---- R4: wires 12..15 (m3..m0); thread: m13..4 = T ----
    {
        #pragma unroll
        for (int r=0;r<16;++r){
            int sm = SWZ((T<<4) | r);
            amp[r] = make_float2(reL[sm], imL[sm]);
        }
        applyw<8>(amp, gatesL+12*4); applyw<4>(amp, gatesL+13*4);
        if (T & 1) swap8u(amp);      // CN(11,12): ctrl m4 = T bit0 (thread-uniform)
        chain3(amp);                 // CN(12,13),(13,14),(14,15)
        if (MEASURE){
            float ps = 0.f;
            #pragma unroll
            for (int r=0;r<16;++r) ps += amp[r].x*amp[r].x + amp[r].y*amp[r].y;
            #pragma unroll
            for (int m=32;m>=1;m>>=1) ps += __shfl_xor(ps, m);
            __syncthreads();
            if ((T & 63) == 0) reL[T>>6] = ps;
            __syncthreads();
            if (T == 0){
                float tot = 0.f;
                #pragma unroll
                for (int k=0;k<16;++k) tot += reL[k];
                float sgn = (c & 2) ? -1.f : 1.f;   // wire0 = c bit1
                atomicAdd(&qacc[b], sgn*tot);
            }
        } else {
            unsigned* po = sout + (((size_t)b<<16) | (c<<14) | (T<<4));
            #pragma unroll
            for (int k2=0;k2<4;++k2){
                uint4 qq;
                qq.x = packh2(amp[k2*4+0]); qq.y = packh2(amp[k2*4+1]);
                qq.z = packh2(amp[k2*4+2]); qq.w = packh2(amp[k2*4+3]);
                *(uint4*)(po + k2*4) = qq;
            }
        }
    }
}

// ---------------- final sigmoid ----------------
__global__ void k_fin(const float* __restrict__ qacc, float* __restrict__ out){
    int i = threadIdx.x;
    if (i < 64) out[i] = 1.f/(1.f + expf(-qacc[i]));
}

extern "C" void kernel_launch(void* const* d_in, const int* in_sizes, int n_in,
                              void* d_out, int out_size, void* d_ws, size_t ws_size,
                              hipStream_t stream){
    (void)in_sizes; (void)n_in; (void)out_size; (void)ws_size;
    const float* x  = (const float*)d_in[0];
    const float* Wc = (const float*)d_in[1];
    const float* bc = (const float*)d_in[2];
    const float* Wr = (const float*)d_in[3];
    const float* br = (const float*)d_in[4];
    const float* wq = (const float*)d_in[5];
    float* ws     = (float*)d_ws;
    float* feat   = ws;
    float* angles = ws + 32768;
    float* qacc   = ws + 33792;
    _Float16* Wh = (_Float16*)((char*)d_ws + ((size_t)1<<20));
    unsigned* SA = (unsigned*)((char*)d_ws + ((size_t)4<<20));
    unsigned* SB = SA + ((size_t)64<<16);
    float* outF = (float*)d_out;

    const int dynG = 32832*4;            // 131328 B
    const int dynI = dynG + 768*8;       // 137472 B
    const int dynC = 224*72*2;           // 32256 B
    hipFuncSetAttribute(reinterpret_cast<const void*>(&k_conv_mfma),
                        hipFuncAttributeMaxDynamicSharedMemorySize, dynC);
    hipFuncSetAttribute(reinterpret_cast<const void*>(&k_vqc<true,false>),
                        hipFuncAttributeMaxDynamicSharedMemorySize, dynI);
    hipFuncSetAttribute(reinterpret_cast<const void*>(&k_vqc<false,false>),
                        hipFuncAttributeMaxDynamicSharedMemorySize, dynG);
    hipFuncSetAttribute(reinterpret_cast<const void*>(&k_vqc<false,true>),
                        hipFuncAttributeMaxDynamicSharedMemorySize, dynG);

    k_zero<<<133,256,0,stream>>>(ws);
    k_prep<<<128,256,0,stream>>>(Wc, Wh);
    k_conv_mfma<<<64*14,512,dynC,stream>>>(x, Wh, bc, feat);
    k_red<<<64,1024,0,stream>>>(feat, Wr, br, angles);
    k_vqc<true ,false><<<256,1024,dynI,stream>>>(wq, angles, nullptr, SA, qacc, 1);
    k_vqc<false,false><<<256,1024,dynG,stream>>>(wq, angles, SA, SB, qacc, 2);
    k_vqc<false,false><<<256,1024,dynG,stream>>>(wq, angles, SB, SA, qacc, 3);
    k_vqc<false,false><<<256,1024,dynG,stream>>>(wq, angles, SA, SB, qacc, 4);
    k_vqc<false,true ><<<256,1024,dynG,stream>>>(wq, angles, SB, SA, qacc, 5);
    k_fin<<<1,64,0,stream>>>(qacc, outF);
}